// Round 11
// baseline (708.420 us; speedup 1.0000x reference)
//
#include <hip/hip_runtime.h>
#include <math.h>

#define D 768
#define DF4 192      // D/4
#define SEQ 128
#define TN 512       // docs per block tile (8 per lane)
#define DLANE 8
#define NCHUNK 48    // 16 floats (64 B) per doc per chunk
#define NBK 64       // top-k blocks per row
#define TOPK 10

#define AS1 __attribute__((address_space(1)))
#define AS3 __attribute__((address_space(3)))

// ---------------- K1: mean over sequence ----------------
__global__ __launch_bounds__(256) void k_mean(const float* __restrict__ q,
                                              float* __restrict__ qmean) {
  int d = blockIdx.x * 256 + threadIdx.x;   // grid.x = 3 -> 768
  int b = blockIdx.y;
  if (d >= D) return;
  const float* p = q + (long)b * SEQ * D + d;
  float s = 0.f;
  #pragma unroll 8
  for (int i = 0; i < SEQ; ++i) s += p[(long)i * D];
  qmean[b * D + d] = s * (1.0f / SEQ);
}

// ---------------- K2: projection + bias + L2 normalize ----------------
__global__ __launch_bounds__(256) void k_proj(const float* __restrict__ qmean,
                                              const float* __restrict__ W,
                                              const float* __restrict__ bias,
                                              float* __restrict__ qnorm) {
  __shared__ float4 qm[DF4];
  __shared__ float red[256];
  int b = blockIdx.x, t = threadIdx.x;
  for (int i = t; i < DF4; i += 256) qm[i] = ((const float4*)qmean)[b * DF4 + i];
  __syncthreads();
  float myout[3];
  #pragma unroll
  for (int i = 0; i < 3; ++i) {
    int j = t + i * 256;
    const float4* wr = (const float4*)W + (long)j * DF4;
    float a0 = 0.f, a1 = 0.f, a2 = 0.f, a3 = 0.f;
    for (int kk = 0; kk < DF4; ++kk) {
      float4 w = wr[kk]; float4 qv = qm[kk];
      a0 = fmaf(w.x, qv.x, a0); a1 = fmaf(w.y, qv.y, a1);
      a2 = fmaf(w.z, qv.z, a2); a3 = fmaf(w.w, qv.w, a3);
    }
    myout[i] = (a0 + a1) + (a2 + a3) + bias[j];
  }
  float ss = myout[0]*myout[0] + myout[1]*myout[1] + myout[2]*myout[2];
  red[t] = ss;
  __syncthreads();
  for (int h = 128; h > 0; h >>= 1) {
    if (t < h) red[t] += red[t + h];
    __syncthreads();
  }
  float rn = 1.0f / fmaxf(sqrtf(red[0]), 1e-12f);
  #pragma unroll
  for (int i = 0; i < 3; ++i) {
    int j = t + i * 256;
    qnorm[b * D + j] = myout[i] * rn;
  }
}

// ---------------- K3: cosine scores (the big one) ----------------
// r11. Fitted law over r6-r10: wall ~ C * (LDS-read instrs) / (blocks/CU).
// r6 18.0M/4=590us, r10 18.0M/4=605 (dbuf==sbuf: staging schedule is NOT the
// binder), r8 14.0M/3*1.13=689 (meas ~700). Attack both terms:
//  - dlane 4->8 (TN=512): q-broadcast reads amortized over 8 docs.
//    Reads/wave-chunk = 64 per 512 docs (vs 48 per 256) -> total LDS instr
//    18.0M -> 12.0M.
//  - Single-buffer 64B-chunk: LDS = 512*64B + 2KB q = 34 KB -> KEEPS 4
//    blocks/CU (the r8 lesson: occupancy enters the law linearly).
//  - blocks = 977 -> 3.82/CU: ONE occupancy round (r10 had 1.91 ragged).
//  - Staging: r8-proven 16-doc x 64B contiguous segments; slot involution
//    (doc>>1)&3 is jj-invariant (jj*16 -> (>>1)*8 == 0 mod 4), so the piece
//    offset is computed once; per-issue byte base = min(base + jj*49152,
//    (N-1)*3072) recomputed per STAGE to hold VGPR pressure down.
//  - 2 barriers/chunk (protect overwrite / drain) — r6-proven sbuf schedule.
//  - q delivery: LDS uniform-address broadcast (r6-proven; SGPR-q dead: r5/r9).
// VGPR ~120 live; waves_per_eu(2,4) + natural alloc (launch_bounds(256,{2,3,4})
// pins 64 VGPR and spills — r1/r3/r4 measured).
__global__ __launch_bounds__(256) __attribute__((amdgpu_waves_per_eu(2, 4)))
void k_scores(const float* __restrict__ docs,
              const float* __restrict__ qn,
              float* __restrict__ outS, int N) {
  __shared__ float4 sD[TN][4];   // 32 KB single buffer
  __shared__ float4 sQ[32][4];   // 2 KB
  const int t = threadIdx.x;
  const int l = t & 63;
  const int w = t >> 6;
  const int sx = (l >> 1) & 3;      // read-side slot XOR
  const long tile0 = (long)blockIdx.x * TN;
  const char* docsb = (const char*)docs;
  const char* qnb = (const char*)qn;

  // Doc-stage: 32 issues/block/chunk; wave w handles i = w*8+jj (jj<8).
  // Issue i: lane l -> doc (tile0 + i*16 + (l>>2)), 64B contiguous per doc.
  const unsigned doc0 = (unsigned)(tile0 + w * 128 + (l >> 2)); // jj=0 doc
  const unsigned pco  = (unsigned)(((l & 3) ^ (int)((doc0 >> 1) & 3)) * 16);
  const unsigned dbyte0 = doc0 * (unsigned)(D * 4);
  const unsigned maxb   = (unsigned)(N - 1) * (unsigned)(D * 4);
  const int du0 = __builtin_amdgcn_readfirstlane(w * 8192);  // i*1024 base
  // q-stage: 2 issues (waves 0,1): lane l -> row (w&1)*16+(l>>2), piece l&3.
  const unsigned qB = (unsigned)(((w & 1) * 16 + (l >> 2)) * (D * 4))
                    + (unsigned)((l & 3) * 16);
  const int qdu = __builtin_amdgcn_readfirstlane((w & 1) * 1024);

#define STAGE(c) do {                                                        \
    unsigned co_ = (unsigned)((c) * 64) + pco;                               \
    char* db_ = (char*)(&sD[0][0]);                                          \
    _Pragma("unroll")                                                        \
    for (int jj_ = 0; jj_ < DLANE; ++jj_) {                                  \
      unsigned b_ = dbyte0 + (unsigned)(jj_ * 16 * D * 4);                   \
      b_ = (b_ < maxb) ? b_ : maxb;                                          \
      __builtin_amdgcn_global_load_lds(                                      \
          (const AS1 void*)(docsb + (b_ + co_)),                             \
          (AS3 void*)(db_ + (du0 + jj_ * 1024)), 16, 0, 0);                  \
    }                                                                        \
    if (w < 2) {                                                             \
      __builtin_amdgcn_global_load_lds(                                      \
          (const AS1 void*)(qnb + (qB + (unsigned)((c) * 64))),              \
          (AS3 void*)((char*)(&sQ[0][0]) + qdu), 16, 0, 0);                  \
    }                                                                        \
  } while (0)

  float acc[8][DLANE];
  #pragma unroll
  for (int i = 0; i < 8; ++i)
    #pragma unroll
    for (int j = 0; j < DLANE; ++j) acc[i][j] = 0.f;
  float ssq[DLANE];
  #pragma unroll
  for (int j = 0; j < DLANE; ++j) ssq[j] = 0.f;

  #pragma unroll 1
  for (int c = 0; c < NCHUNK; ++c) {
    __syncthreads();          // all waves done reading chunk c-1
    STAGE(c);
    __syncthreads();          // own DMAs drained (implicit vmcnt0) + join
    #pragma unroll
    for (int s = 0; s < 4; ++s) {
      float4 dv[DLANE];
      #pragma unroll
      for (int dj = 0; dj < DLANE; ++dj) {
        dv[dj] = sD[l + dj * 64][s ^ sx];
        ssq[dj] = fmaf(dv[dj].x, dv[dj].x, ssq[dj]);
        ssq[dj] = fmaf(dv[dj].y, dv[dj].y, ssq[dj]);
        ssq[dj] = fmaf(dv[dj].z, dv[dj].z, ssq[dj]);
        ssq[dj] = fmaf(dv[dj].w, dv[dj].w, ssq[dj]);
      }
      #pragma unroll
      for (int qi = 0; qi < 8; ++qi) {
        float4 q4 = sQ[w * 8 + qi][s];      // uniform addr -> broadcast
        #pragma unroll
        for (int dj = 0; dj < DLANE; ++dj) {
          acc[qi][dj] = fmaf(q4.x, dv[dj].x, acc[qi][dj]);
          acc[qi][dj] = fmaf(q4.y, dv[dj].y, acc[qi][dj]);
          acc[qi][dj] = fmaf(q4.z, dv[dj].z, acc[qi][dj]);
          acc[qi][dj] = fmaf(q4.w, dv[dj].w, acc[qi][dj]);
        }
      }
    }
  }
#undef STAGE

  #pragma unroll
  for (int dj = 0; dj < DLANE; ++dj) {
    long gd = tile0 + l + dj * 64;
    if (gd < N) {
      float rn = 1.0f / fmaxf(sqrtf(ssq[dj]), 1e-12f);
      #pragma unroll
      for (int qi = 0; qi < 8; ++qi)
        outS[(long)(w * 8 + qi) * N + gd] = acc[qi][dj] * rn;  // coalesced
    }
  }
}

// ---------------- top-k helpers ----------------
// ranks-before comparator: higher score wins; tie -> smaller index (lax.top_k stable)
__device__ __forceinline__ void insert10(float v, float p, float bs[10], float bi[10]) {
  bool last = (v > bs[9]) || (v == bs[9] && p < bi[9]);
  if (!last) return;
  #pragma unroll
  for (int j = 9; j >= 1; --j) {     // static indices only (no scratch)
    bool bj  = (v > bs[j])   || (v == bs[j]   && p < bi[j]);
    bool bjm = (v > bs[j-1]) || (v == bs[j-1] && p < bi[j-1]);
    float ns = bj ? (bjm ? bs[j-1] : v) : bs[j];
    float ni = bj ? (bjm ? bi[j-1] : p) : bi[j];
    bs[j] = ns; bi[j] = ni;
  }
  bool b0 = (v > bs[0]) || (v == bs[0] && p < bi[0]);
  if (b0) { bs[0] = v; bi[0] = p; }
}

// ---------------- K4: per-(row, segment) top-10 ----------------
__global__ __launch_bounds__(256) void k_topblk(const float* __restrict__ scores,
                                                float2* __restrict__ btop, int N) {
  const int row = blockIdx.y, seg = blockIdx.x, t = threadIdx.x;
  const int per = (N + NBK - 1) / NBK;
  const int s0 = seg * per;
  const int s1 = (s0 + per < N) ? (s0 + per) : N;
  const float* rp = scores + (long)row * N;
  float bs[10], bi[10];
  #pragma unroll
  for (int k = 0; k < 10; ++k) { bs[k] = -INFINITY; bi[k] = 2.0e9f; }
  for (int p = s0 + t; p < s1; p += 256) insert10(rp[p], (float)p, bs, bi);

  __shared__ float ms[256][10];
  __shared__ float mi[256][10];
  #pragma unroll
  for (int k = 0; k < 10; ++k) { ms[t][k] = bs[k]; mi[t][k] = bi[k]; }
  __syncthreads();
  for (int h = 128; h > 0; h >>= 1) {
    if (t < h) {
      float os[10], oi[10];
      int x = 0, y = 0;
      #pragma unroll
      for (int k = 0; k < 10; ++k) {
        float sx = ms[t][x], sy = ms[t + h][y];
        float ix = mi[t][x], iy = mi[t + h][y];
        bool ta = (sx > sy) || (sx == sy && ix < iy);
        os[k] = ta ? sx : sy; oi[k] = ta ? ix : iy;
        x += ta ? 1 : 0; y += ta ? 0 : 1;
      }
      #pragma unroll
      for (int k = 0; k < 10; ++k) { ms[t][k] = os[k]; mi[t][k] = oi[k]; }
    }
    __syncthreads();
  }
  if (t == 0) {
    #pragma unroll
    for (int k = 0; k < 10; ++k)
      btop[((long)row * NBK + seg) * 10 + k] = make_float2(ms[0][k], mi[0][k]);
  }
}

// ---------------- K5: final merge per row, write indices as float ----------------
__global__ __launch_bounds__(256) void k_topfinal(const float2* __restrict__ btop,
                                                  float* __restrict__ outIdx) {
  const int row = blockIdx.x, t = threadIdx.x;
  const int M = NBK * 10;   // 640 candidates
  float bs[10], bi[10];
  #pragma unroll
  for (int k = 0; k < 10; ++k) { bs[k] = -INFINITY; bi[k] = 2.0e9f; }
  for (int p = t; p < M; p += 256) {
    float2 c = btop[(long)row * M + p];
    insert10(c.x, c.y, bs, bi);
  }
  __shared__ float ms[256][10];
  __shared__ float mi[256][10];
  #pragma unroll
  for (int k = 0; k < 10; ++k) { ms[t][k] = bs[k]; mi[t][k] = bi[k]; }
  __syncthreads();
  for (int h = 128; h > 0; h >>= 1) {
    if (t < h) {
      float os[10], oi[10];
      int x = 0, y = 0;
      #pragma unroll
      for (int k = 0; k < 10; ++k) {
        float sx = ms[t][x], sy = ms[t + h][y];
        float ix = mi[t][x], iy = mi[t + h][y];
        bool ta = (sx > sy) || (sx == sy && ix < iy);
        os[k] = ta ? sx : sy; oi[k] = ta ? ix : iy;
        x += ta ? 1 : 0; y += ta ? 0 : 1;
      }
      #pragma unroll
      for (int k = 0; k < 10; ++k) { ms[t][k] = os[k]; mi[t][k] = oi[k]; }
    }
    __syncthreads();
  }
  if (t == 0) {
    #pragma unroll
    for (int k = 0; k < 10; ++k) outIdx[row * TOPK + k] = mi[0][k];
  }
}

extern "C" void kernel_launch(void* const* d_in, const int* in_sizes, int n_in,
                              void* d_out, int out_size, void* d_ws, size_t ws_size,
                              hipStream_t stream) {
  const float* q    = (const float*)d_in[0];   // [32,128,768]
  const float* docs = (const float*)d_in[1];   // [N,768]
  const float* W    = (const float*)d_in[2];   // [768,768]
  const float* bias = (const float*)d_in[3];   // [768]
  const int B = in_sizes[0] / (SEQ * D);       // 32
  const int N = in_sizes[1] / D;               // 500000

  float* out    = (float*)d_out;
  float* outIdx = out;                          // [B*10] indices as float
  float* outS   = out + (long)B * TOPK;         // [B][N] scores

  float*  qmean = (float*)d_ws;                 // B*D
  float*  qnorm = qmean + (long)B * D;          // B*D
  float2* btop  = (float2*)(qnorm + (long)B * D); // B*NBK*10 pairs

  dim3 g1(3, B);
  k_mean<<<g1, 256, 0, stream>>>(q, qmean);
  k_proj<<<B, 256, 0, stream>>>(qmean, W, bias, qnorm);
  int ntiles = (N + TN - 1) / TN;
  k_scores<<<ntiles, 256, 0, stream>>>(docs, qnorm, outS, N);
  dim3 g4(NBK, B);
  k_topblk<<<g4, 256, 0, stream>>>(outS, btop, N);
  k_topfinal<<<B, 256, 0, stream>>>(btop, outIdx);
}

// Round 12
// 603.057 us; speedup vs baseline: 1.1747x; 1.1747x over previous
//
#include <hip/hip_runtime.h>
#include <math.h>

#define D 768
#define DF4 192      // D/4
#define SEQ 128
#define TN 256       // docs per block tile
#define NBK 64       // top-k segments per row
#define TOPK 10
#define KSTEPS 24    // 768 / 32

typedef __attribute__((ext_vector_type(8))) short bh8;    // 8 bf16 = 4 VGPR
typedef __attribute__((ext_vector_type(4))) float f32x4;

#define AS1 __attribute__((address_space(1)))
#define AS3 __attribute__((address_space(3)))

__device__ __forceinline__ unsigned short f2bf(float f) {  // RTNE f32->bf16
  unsigned u = __float_as_uint(f);
  return (unsigned short)((u + 0x7FFF + ((u >> 16) & 1)) >> 16);
}

// ---------------- K1: mean over sequence ----------------
__global__ __launch_bounds__(256) void k_mean(const float* __restrict__ q,
                                              float* __restrict__ qmean) {
  int d = blockIdx.x * 256 + threadIdx.x;
  int b = blockIdx.y;
  if (d >= D) return;
  const float* p = q + (long)b * SEQ * D + d;
  float s = 0.f;
  #pragma unroll 8
  for (int i = 0; i < SEQ; ++i) s += p[(long)i * D];
  qmean[b * D + d] = s * (1.0f / SEQ);
}

// ---------------- K2: projection + bias + L2 normalize ----------------
// Also emits a bf16 copy of qnorm PRE-SWIZZLED for k_scores' A-LDS
// (slot' = slot ^ (row&7) on 16B slots) so the A tile can be DMA'd linearly.
__global__ __launch_bounds__(256) void k_proj(const float* __restrict__ qmean,
                                              const float* __restrict__ W,
                                              const float* __restrict__ bias,
                                              float* __restrict__ qnorm,
                                              unsigned short* __restrict__ qbf) {
  __shared__ float4 qm[DF4];
  __shared__ float red[256];
  int b = blockIdx.x, t = threadIdx.x;
  for (int i = t; i < DF4; i += 256) qm[i] = ((const float4*)qmean)[b * DF4 + i];
  __syncthreads();
  float myout[3];
  #pragma unroll
  for (int i = 0; i < 3; ++i) {
    int j = t + i * 256;
    const float4* wr = (const float4*)W + (long)j * DF4;
    float a0 = 0.f, a1 = 0.f, a2 = 0.f, a3 = 0.f;
    for (int kk = 0; kk < DF4; ++kk) {
      float4 w = wr[kk]; float4 qv = qm[kk];
      a0 = fmaf(w.x, qv.x, a0); a1 = fmaf(w.y, qv.y, a1);
      a2 = fmaf(w.z, qv.z, a2); a3 = fmaf(w.w, qv.w, a3);
    }
    myout[i] = (a0 + a1) + (a2 + a3) + bias[j];
  }
  float ss = myout[0]*myout[0] + myout[1]*myout[1] + myout[2]*myout[2];
  red[t] = ss;
  __syncthreads();
  for (int h = 128; h > 0; h >>= 1) {
    if (t < h) red[t] += red[t + h];
    __syncthreads();
  }
  float rn = 1.0f / fmaxf(sqrtf(red[0]), 1e-12f);
  #pragma unroll
  for (int i = 0; i < 3; ++i) {
    int j = t + i * 256;
    float v = myout[i] * rn;
    qnorm[b * D + j] = v;
    int slot = j >> 3;
    qbf[b * D + ((slot ^ (b & 7)) << 3) + (j & 7)] = f2bf(v);
  }
}

// ---------------- K3: cosine scores via MFMA bf16 ----------------
// Rounds 6-11 proved the scalar-FMA structure is LDS-return-bus bound
// (~70k b128 wave-instrs/CU = 352us; wall 590-750 across all schedules).
// MFMA reuses each fragment across 256 MACs: LDS drops to ~4.4k instrs/CU
// (~22us), MFMA pipe ~12us -> HBM-bound (~254us).
//  - C = A(32q x 768) x B(768 x docs). 16x16x32 bf16. Block: 4 waves, 256
//    docs; wave w: docs [w*64,w*64+64) = 4 N-tiles; both M-tiles. acc[2][4].
//  - A: bf16 swizzled 48KB LDS, DMA'd once from qbf. Frag: lane l -> row
//    (mt*16+(l&15)), k-slot (c*4+(l>>4))^(row&7). 2 lanes/bank = free.
//  - B: per K-step 256 docs x 32k staged f32->regs (8x dwordx4, 8 docs x
//    128B contiguous per wave-instr), RTNE cvt, ds_write_b64 to swizzled
//    bf16 rows [doc][64B], slot^((doc>>1)&3). dbuf 2x16KB. ssq accumulated
//    in f32 from the staged regs (exact norms).
//  - Schedule: loads(c+1)->regs; MFMA(c); cvt+write(c+1); one barrier.
//  - LDS 48+32=80KB -> 2 blocks/CU; VGPR ~110 (acc32+stage32+frags+addr).
//  - Top-k exactness is NOT required of these scores (error ~1e-4): k_rescore
//    re-scores segment winners in exact f32.
__global__ __launch_bounds__(256) __attribute__((amdgpu_waves_per_eu(2, 4)))
void k_scores(const float* __restrict__ docs,
              const unsigned short* __restrict__ qbf,
              float* __restrict__ outS, int N) {
  __shared__ f32x4 smem4[81920 / 16];   // 80 KB: A[0,48K) + B dbuf [48K,80K)
  char* sm = (char*)smem4;
  const int t = threadIdx.x, l = t & 63, w = t >> 6;
  const long tile0 = (long)blockIdx.x * TN;
  const char* docsb = (const char*)docs;

  // --- A DMA: 48 KB linear (qbf already swizzled) ---
  {
    const char* qb = (const char*)qbf;
    #pragma unroll
    for (int i = 0; i < 12; ++i) {
      int off = __builtin_amdgcn_readfirstlane((w * 12 + i) << 10);
      __builtin_amdgcn_global_load_lds((const AS1 void*)(qb + off + l * 16),
                                       (AS3 void*)(sm + off), 16, 0, 0);
    }
  }

  // --- staging addresses ---
  // issue j: lane l -> doc (tile0 + w*64 + j*8 + (l>>3)), k-part (l&7)*16B.
  unsigned gbase[8];
  #pragma unroll
  for (int j = 0; j < 8; ++j) {
    long g = tile0 + w * 64 + j * 8 + (l >> 3);
    if (g >= N) g = N - 1;
    gbase[j] = (unsigned)(g * (D * 4)) + (unsigned)((l & 7) * 16);
  }
  // LDS write addr (relative to B buf base); j-stride 512 (swizzle j-invariant)
  int wa0;
  {
    int dl = w * 64 + (l >> 3);
    int slot = (l & 7) >> 1, h = (l & 7) & 1;
    wa0 = dl * 64 + ((slot ^ ((dl >> 1) & 3)) << 4) + h * 8;
  }

  f32x4 rg[8];
  float ssqp[8];
  #pragma unroll
  for (int j = 0; j < 8; ++j) ssqp[j] = 0.f;
  f32x4 acc[2][4];
  #pragma unroll
  for (int m = 0; m < 2; ++m)
    #pragma unroll
    for (int n = 0; n < 4; ++n) acc[m][n] = (f32x4){0.f, 0.f, 0.f, 0.f};

#define LOADREG(c) do {                                                      \
    unsigned co_ = (unsigned)((c) * 128);                                    \
    _Pragma("unroll")                                                        \
    for (int j_ = 0; j_ < 8; ++j_)                                           \
      rg[j_] = *(const f32x4*)(docsb + (gbase[j_] + co_));                   \
  } while (0)

#define CVTWRITE(buf) do {                                                   \
    char* bb_ = sm + 49152 + (buf) * 16384;                                  \
    _Pragma("unroll")                                                        \
    for (int j_ = 0; j_ < 8; ++j_) {                                         \
      f32x4 v_ = rg[j_];                                                     \
      ssqp[j_] = fmaf(v_.x, v_.x, ssqp[j_]);                                 \
      ssqp[j_] = fmaf(v_.y, v_.y, ssqp[j_]);                                 \
      ssqp[j_] = fmaf(v_.z, v_.z, ssqp[j_]);                                 \
      ssqp[j_] = fmaf(v_.w, v_.w, ssqp[j_]);                                 \
      ushort4 u_;                                                            \
      u_.x = f2bf(v_.x); u_.y = f2bf(v_.y);                                  \
      u_.z = f2bf(v_.z); u_.w = f2bf(v_.w);                                  \
      *(ushort4*)(bb_ + (wa0 + j_ * 512)) = u_;                              \
    }                                                                        \
  } while (0)

  // prologue: stage K-step 0
  LOADREG(0);
  CVTWRITE(0);
  __syncthreads();          // A + B-buf0 ready
  int cur = 0;

  #pragma unroll 1
  for (int c = 0; c < KSTEPS; ++c) {
    if (c + 1 < KSTEPS) LOADREG(c + 1);
    {  // compute on buf cur
      const char* bb = sm + 49152 + cur * 16384;
      bh8 aF[2];
      int sA0 = c * 4 + (l >> 4);
      #pragma unroll
      for (int m = 0; m < 2; ++m) {
        int r = m * 16 + (l & 15);
        aF[m] = *(const bh8*)(sm + r * 1536 + ((sA0 ^ (r & 7)) << 4));
      }
      #pragma unroll
      for (int n = 0; n < 4; ++n) {
        int dl = w * 64 + n * 16 + (l & 15);
        bh8 bF = *(const bh8*)(bb + dl * 64 + ((((l >> 4)) ^ ((dl >> 1) & 3)) << 4));
        acc[0][n] = __builtin_amdgcn_mfma_f32_16x16x32_bf16(aF[0], bF, acc[0][n], 0, 0, 0);
        acc[1][n] = __builtin_amdgcn_mfma_f32_16x16x32_bf16(aF[1], bF, acc[1][n], 0, 0, 0);
      }
    }
    if (c + 1 < KSTEPS) CVTWRITE(cur ^ 1);
    __syncthreads();
    cur ^= 1;
  }
#undef LOADREG
#undef CVTWRITE

  // --- doc norms: reduce k-slices across the 8 lanes of each doc group ---
  #pragma unroll
  for (int j = 0; j < 8; ++j) {
    ssqp[j] += __shfl_xor(ssqp[j], 1);
    ssqp[j] += __shfl_xor(ssqp[j], 2);
    ssqp[j] += __shfl_xor(ssqp[j], 4);
  }
  float* sSQ = (float*)(sm + 49152);   // overlay on dead B region
  if ((l & 7) == 0) {
    #pragma unroll
    for (int j = 0; j < 8; ++j) sSQ[w * 64 + j * 8 + (l >> 3)] = ssqp[j];
  }
  __syncthreads();

  // --- C write: col=lane&15, row=(lane>>4)*4+reg (m89-verified) ---
  #pragma unroll
  for (int n = 0; n < 4; ++n) {
    int dl = w * 64 + n * 16 + (l & 15);
    long g = tile0 + dl;
    if (g < N) {
      float rn = 1.0f / fmaxf(sqrtf(sSQ[dl]), 1e-12f);
      #pragma unroll
      for (int m = 0; m < 2; ++m) {
        #pragma unroll
        for (int r = 0; r < 4; ++r) {
          int qrow = m * 16 + (l >> 4) * 4 + r;
          outS[(long)qrow * N + g] = acc[m][n][r] * rn;
        }
      }
    }
  }
}

// ---------------- top-k helpers ----------------
__device__ __forceinline__ void insert10(float v, float p, float bs[10], float bi[10]) {
  bool last = (v > bs[9]) || (v == bs[9] && p < bi[9]);
  if (!last) return;
  #pragma unroll
  for (int j = 9; j >= 1; --j) {
    bool bj  = (v > bs[j])   || (v == bs[j]   && p < bi[j]);
    bool bjm = (v > bs[j-1]) || (v == bs[j-1] && p < bi[j-1]);
    float ns = bj ? (bjm ? bs[j-1] : v) : bs[j];
    float ni = bj ? (bjm ? bi[j-1] : p) : bi[j];
    bs[j] = ns; bi[j] = ni;
  }
  bool b0 = (v > bs[0]) || (v == bs[0] && p < bi[0]);
  if (b0) { bs[0] = v; bi[0] = p; }
}

// ---------------- K4: per-(row, segment) top-10 on MFMA scores ----------------
__global__ __launch_bounds__(256) void k_topblk(const float* __restrict__ scores,
                                                float2* __restrict__ btop, int N) {
  const int row = blockIdx.y, seg = blockIdx.x, t = threadIdx.x;
  const int per = (N + NBK - 1) / NBK;
  const int s0 = seg * per;
  const int s1 = (s0 + per < N) ? (s0 + per) : N;
  const float* rp = scores + (long)row * N;
  float bs[10], bi[10];
  #pragma unroll
  for (int k = 0; k < 10; ++k) { bs[k] = -INFINITY; bi[k] = 2.0e9f; }
  for (int p = s0 + t; p < s1; p += 256) insert10(rp[p], (float)p, bs, bi);

  __shared__ float ms[256][10];
  __shared__ float mi[256][10];
  #pragma unroll
  for (int k = 0; k < 10; ++k) { ms[t][k] = bs[k]; mi[t][k] = bi[k]; }
  __syncthreads();
  for (int h = 128; h > 0; h >>= 1) {
    if (t < h) {
      float os[10], oi[10];
      int x = 0, y = 0;
      #pragma unroll
      for (int k = 0; k < 10; ++k) {
        float sx = ms[t][x], sy = ms[t + h][y];
        float ix = mi[t][x], iy = mi[t + h][y];
        bool ta = (sx > sy) || (sx == sy && ix < iy);
        os[k] = ta ? sx : sy; oi[k] = ta ? ix : iy;
        x += ta ? 1 : 0; y += ta ? 0 : 1;
      }
      #pragma unroll
      for (int k = 0; k < 10; ++k) { ms[t][k] = os[k]; mi[t][k] = oi[k]; }
    }
    __syncthreads();
  }
  if (t == 0) {
    #pragma unroll
    for (int k = 0; k < 10; ++k)
      btop[((long)row * NBK + seg) * 10 + k] = make_float2(ms[0][k], mi[0][k]);
  }
}

// ---------------- K5: exact f32 rescore of 640 candidates -> top-10 ----------
// MFMA scores carry ~1e-4 error vs rank-10 gaps ~7e-3: candidates (union of
// per-segment top-10, true top-10 guaranteed inside) are re-scored exactly in
// f32 from original docs, so indices match the reference ranking.
__global__ __launch_bounds__(256) void k_rescore(const float* __restrict__ docs,
                                                 const float* __restrict__ qn,
                                                 const float2* __restrict__ btop,
                                                 float* __restrict__ outIdx, int N) {
  const int row = blockIdx.x, t = threadIdx.x;
  const int M = NBK * 10;   // 640
  __shared__ float4 qrow[DF4];
  __shared__ float cs[M];
  __shared__ float ci[M];
  if (t < DF4) qrow[t] = ((const float4*)qn)[row * DF4 + t];
  __syncthreads();
  for (int cand = t; cand < M; cand += 256) {
    float2 c = btop[(long)row * M + cand];
    int doc = (int)c.y;
    const float4* dp = (const float4*)docs + (long)doc * DF4;
    float a0 = 0.f, a1 = 0.f, a2 = 0.f, a3 = 0.f;
    float s0 = 0.f, s1 = 0.f, s2 = 0.f, s3 = 0.f;
    for (int kk = 0; kk < DF4; ++kk) {
      float4 d4 = dp[kk]; float4 q4 = qrow[kk];
      a0 = fmaf(q4.x, d4.x, a0); a1 = fmaf(q4.y, d4.y, a1);
      a2 = fmaf(q4.z, d4.z, a2); a3 = fmaf(q4.w, d4.w, a3);
      s0 = fmaf(d4.x, d4.x, s0); s1 = fmaf(d4.y, d4.y, s1);
      s2 = fmaf(d4.z, d4.z, s2); s3 = fmaf(d4.w, d4.w, s3);
    }
    float nrm = sqrtf((s0 + s1) + (s2 + s3));
    cs[cand] = ((a0 + a1) + (a2 + a3)) / fmaxf(nrm, 1e-12f);
    ci[cand] = c.y;
  }
  __syncthreads();
  float bs[10], bi[10];
  #pragma unroll
  for (int k = 0; k < 10; ++k) { bs[k] = -INFINITY; bi[k] = 2.0e9f; }
  for (int cand = t; cand < M; cand += 256) insert10(cs[cand], ci[cand], bs, bi);

  __shared__ float ms[256][10];
  __shared__ float mi[256][10];
  #pragma unroll
  for (int k = 0; k < 10; ++k) { ms[t][k] = bs[k]; mi[t][k] = bi[k]; }
  __syncthreads();
  for (int h = 128; h > 0; h >>= 1) {
    if (t < h) {
      float os[10], oi[10];
      int x = 0, y = 0;
      #pragma unroll
      for (int k = 0; k < 10; ++k) {
        float sx = ms[t][x], sy = ms[t + h][y];
        float ix = mi[t][x], iy = mi[t + h][y];
        bool ta = (sx > sy) || (sx == sy && ix < iy);
        os[k] = ta ? sx : sy; oi[k] = ta ? ix : iy;
        x += ta ? 1 : 0; y += ta ? 0 : 1;
      }
      #pragma unroll
      for (int k = 0; k < 10; ++k) { ms[t][k] = os[k]; mi[t][k] = oi[k]; }
    }
    __syncthreads();
  }
  if (t == 0) {
    #pragma unroll
    for (int k = 0; k < 10; ++k) outIdx[row * TOPK + k] = mi[0][k];
  }
}

extern "C" void kernel_launch(void* const* d_in, const int* in_sizes, int n_in,
                              void* d_out, int out_size, void* d_ws, size_t ws_size,
                              hipStream_t stream) {
  const float* q    = (const float*)d_in[0];   // [32,128,768]
  const float* docs = (const float*)d_in[1];   // [N,768]
  const float* W    = (const float*)d_in[2];   // [768,768]
  const float* bias = (const float*)d_in[3];   // [768]
  const int B = in_sizes[0] / (SEQ * D);       // 32
  const int N = in_sizes[1] / D;               // 500000

  float* out    = (float*)d_out;
  float* outIdx = out;                          // [B*10] indices as float
  float* outS   = out + (long)B * TOPK;         // [B][N] scores

  float* qmean = (float*)d_ws;                               // B*D f32
  float* qnorm = qmean + (long)B * D;                        // B*D f32
  unsigned short* qbf = (unsigned short*)(qnorm + (long)B * D); // B*D bf16 (swizzled)
  float2* btop = (float2*)((char*)qbf + (long)B * D * 2);    // B*NBK*10 pairs

  dim3 g1(3, B);
  k_mean<<<g1, 256, 0, stream>>>(q, qmean);
  k_proj<<<B, 256, 0, stream>>>(qmean, W, bias, qnorm, qbf);
  int ntiles = (N + TN - 1) / TN;
  k_scores<<<ntiles, 256, 0, stream>>>(docs, qbf, outS, N);
  dim3 g4(NBK, B);
  k_topblk<<<g4, 256, 0, stream>>>(outS, btop, N);
  k_rescore<<<B, 256, 0, stream>>>(docs, qnorm, btop, outIdx, N);
}

// Round 13
// 527.094 us; speedup vs baseline: 1.3440x; 1.1441x over previous
//
#include <hip/hip_runtime.h>
#include <math.h>

#define D 768
#define DF4 192      // D/4
#define SEQ 128
#define TN 256       // docs per block tile
#define NBK 64       // top-k segments per row
#define TOPK 10
#define KSTEPS 24    // 768 / 32
#define NSEG 8       // rescore segments per row
#define CPS 80       // candidates per rescore segment (640/8)

typedef __attribute__((ext_vector_type(8))) short bh8;    // 8 bf16 = 4 VGPR
typedef __attribute__((ext_vector_type(4))) float f32x4;

#define AS1 __attribute__((address_space(1)))
#define AS3 __attribute__((address_space(3)))

__device__ __forceinline__ unsigned short f2bf(float f) {  // RTNE f32->bf16
  unsigned u = __float_as_uint(f);
  return (unsigned short)((u + 0x7FFF + ((u >> 16) & 1)) >> 16);
}

// ---------------- K1: mean over sequence ----------------
__global__ __launch_bounds__(256) void k_mean(const float* __restrict__ q,
                                              float* __restrict__ qmean) {
  int d = blockIdx.x * 256 + threadIdx.x;
  int b = blockIdx.y;
  if (d >= D) return;
  const float* p = q + (long)b * SEQ * D + d;
  float s = 0.f;
  #pragma unroll 8
  for (int i = 0; i < SEQ; ++i) s += p[(long)i * D];
  qmean[b * D + d] = s * (1.0f / SEQ);
}

// ---------------- K2: projection + bias + L2 normalize ----------------
// Emits bf16 qnorm PRE-SWIZZLED (slot' = slot ^ (row&7)) for k_scores' A-LDS.
__global__ __launch_bounds__(256) void k_proj(const float* __restrict__ qmean,
                                              const float* __restrict__ W,
                                              const float* __restrict__ bias,
                                              float* __restrict__ qnorm,
                                              unsigned short* __restrict__ qbf) {
  __shared__ float4 qm[DF4];
  __shared__ float red[256];
  int b = blockIdx.x, t = threadIdx.x;
  for (int i = t; i < DF4; i += 256) qm[i] = ((const float4*)qmean)[b * DF4 + i];
  __syncthreads();
  float myout[3];
  #pragma unroll
  for (int i = 0; i < 3; ++i) {
    int j = t + i * 256;
    const float4* wr = (const float4*)W + (long)j * DF4;
    float a0 = 0.f, a1 = 0.f, a2 = 0.f, a3 = 0.f;
    for (int kk = 0; kk < DF4; ++kk) {
      float4 w = wr[kk]; float4 qv = qm[kk];
      a0 = fmaf(w.x, qv.x, a0); a1 = fmaf(w.y, qv.y, a1);
      a2 = fmaf(w.z, qv.z, a2); a3 = fmaf(w.w, qv.w, a3);
    }
    myout[i] = (a0 + a1) + (a2 + a3) + bias[j];
  }
  float ss = myout[0]*myout[0] + myout[1]*myout[1] + myout[2]*myout[2];
  red[t] = ss;
  __syncthreads();
  for (int h = 128; h > 0; h >>= 1) {
    if (t < h) red[t] += red[t + h];
    __syncthreads();
  }
  float rn = 1.0f / fmaxf(sqrtf(red[0]), 1e-12f);
  #pragma unroll
  for (int i = 0; i < 3; ++i) {
    int j = t + i * 256;
    float v = myout[i] * rn;
    qnorm[b * D + j] = v;
    int slot = j >> 3;
    qbf[b * D + ((slot ^ (b & 7)) << 3) + (j & 7)] = f2bf(v);
  }
}

// ---------------- K3: cosine scores via MFMA bf16 ----------------
// r12-proven numerics/swizzles (passed, absmax 9.8e-4). r13 change: the
// waves_per_eu attribute is min-ONLY (2) — r12's (2,4) max invited the
// allocator to chase a 128-VGPR budget and (suspected) spill the ~110-live
// state + unroll transients; this toolchain spills rather than relaxing
// occupancy (r1/r3/r4: launch_bounds(256,{2,3,4}) pin 64 VGPR and spill GBs).
__global__ __launch_bounds__(256) __attribute__((amdgpu_waves_per_eu(2)))
void k_scores(const float* __restrict__ docs,
              const unsigned short* __restrict__ qbf,
              float* __restrict__ outS, int N) {
  __shared__ f32x4 smem4[81920 / 16];   // 80 KB: A[0,48K) + B dbuf [48K,80K)
  char* sm = (char*)smem4;
  const int t = threadIdx.x, l = t & 63, w = t >> 6;
  const long tile0 = (long)blockIdx.x * TN;
  const char* docsb = (const char*)docs;

  // --- A DMA: 48 KB linear (qbf already swizzled) ---
  {
    const char* qb = (const char*)qbf;
    #pragma unroll
    for (int i = 0; i < 12; ++i) {
      int off = __builtin_amdgcn_readfirstlane((w * 12 + i) << 10);
      __builtin_amdgcn_global_load_lds((const AS1 void*)(qb + off + l * 16),
                                       (AS3 void*)(sm + off), 16, 0, 0);
    }
  }

  // --- staging addresses ---
  // issue j: lane l -> doc (tile0 + w*64 + j*8 + (l>>3)), k-part (l&7)*16B.
  unsigned gbase[8];
  #pragma unroll
  for (int j = 0; j < 8; ++j) {
    long g = tile0 + w * 64 + j * 8 + (l >> 3);
    if (g >= N) g = N - 1;
    gbase[j] = (unsigned)(g * (D * 4)) + (unsigned)((l & 7) * 16);
  }
  // LDS write addr (relative to B buf base); j-stride 512 (swizzle j-invariant)
  int wa0;
  {
    int dl = w * 64 + (l >> 3);
    int slot = (l & 7) >> 1, h = (l & 7) & 1;
    wa0 = dl * 64 + ((slot ^ ((dl >> 1) & 3)) << 4) + h * 8;
  }

  f32x4 rg[8];
  float ssqp[8];
  #pragma unroll
  for (int j = 0; j < 8; ++j) ssqp[j] = 0.f;
  f32x4 acc[2][4];
  #pragma unroll
  for (int m = 0; m < 2; ++m)
    #pragma unroll
    for (int n = 0; n < 4; ++n) acc[m][n] = (f32x4){0.f, 0.f, 0.f, 0.f};

#define LOADREG(c) do {                                                      \
    unsigned co_ = (unsigned)((c) * 128);                                    \
    _Pragma("unroll")                                                        \
    for (int j_ = 0; j_ < 8; ++j_)                                           \
      rg[j_] = *(const f32x4*)(docsb + (gbase[j_] + co_));                   \
  } while (0)

#define CVTWRITE(buf) do {                                                   \
    char* bb_ = sm + 49152 + (buf) * 16384;                                  \
    _Pragma("unroll")                                                        \
    for (int j_ = 0; j_ < 8; ++j_) {                                         \
      f32x4 v_ = rg[j_];                                                     \
      ssqp[j_] = fmaf(v_.x, v_.x, ssqp[j_]);                                 \
      ssqp[j_] = fmaf(v_.y, v_.y, ssqp[j_]);                                 \
      ssqp[j_] = fmaf(v_.z, v_.z, ssqp[j_]);                                 \
      ssqp[j_] = fmaf(v_.w, v_.w, ssqp[j_]);                                 \
      ushort4 u_;                                                            \
      u_.x = f2bf(v_.x); u_.y = f2bf(v_.y);                                  \
      u_.z = f2bf(v_.z); u_.w = f2bf(v_.w);                                  \
      *(ushort4*)(bb_ + (wa0 + j_ * 512)) = u_;                              \
    }                                                                        \
  } while (0)

  LOADREG(0);
  CVTWRITE(0);
  __syncthreads();          // A + B-buf0 ready
  int cur = 0;

  #pragma unroll 1
  for (int c = 0; c < KSTEPS; ++c) {
    if (c + 1 < KSTEPS) LOADREG(c + 1);
    {  // compute on buf cur
      const char* bb = sm + 49152 + cur * 16384;
      bh8 aF[2];
      int sA0 = c * 4 + (l >> 4);
      #pragma unroll
      for (int m = 0; m < 2; ++m) {
        int r = m * 16 + (l & 15);
        aF[m] = *(const bh8*)(sm + r * 1536 + ((sA0 ^ (r & 7)) << 4));
      }
      #pragma unroll
      for (int n = 0; n < 4; ++n) {
        int dl = w * 64 + n * 16 + (l & 15);
        bh8 bF = *(const bh8*)(bb + dl * 64 + ((((l >> 4)) ^ ((dl >> 1) & 3)) << 4));
        acc[0][n] = __builtin_amdgcn_mfma_f32_16x16x32_bf16(aF[0], bF, acc[0][n], 0, 0, 0);
        acc[1][n] = __builtin_amdgcn_mfma_f32_16x16x32_bf16(aF[1], bF, acc[1][n], 0, 0, 0);
      }
    }
    if (c + 1 < KSTEPS) CVTWRITE(cur ^ 1);
    __syncthreads();
    cur ^= 1;
  }
#undef LOADREG
#undef CVTWRITE

  // --- doc norms: reduce k-slices across the 8 lanes of each doc group ---
  #pragma unroll
  for (int j = 0; j < 8; ++j) {
    ssqp[j] += __shfl_xor(ssqp[j], 1);
    ssqp[j] += __shfl_xor(ssqp[j], 2);
    ssqp[j] += __shfl_xor(ssqp[j], 4);
  }
  float* sSQ = (float*)(sm + 49152);
  if ((l & 7) == 0) {
    #pragma unroll
    for (int j = 0; j < 8; ++j) sSQ[w * 64 + j * 8 + (l >> 3)] = ssqp[j];
  }
  __syncthreads();

  // --- C write: col=lane&15, row=(lane>>4)*4+reg (m89-verified) ---
  #pragma unroll
  for (int n = 0; n < 4; ++n) {
    int dl = w * 64 + n * 16 + (l & 15);
    long g = tile0 + dl;
    if (g < N) {
      float rn = 1.0f / fmaxf(sqrtf(sSQ[dl]), 1e-12f);
      #pragma unroll
      for (int m = 0; m < 2; ++m) {
        #pragma unroll
        for (int r = 0; r < 4; ++r) {
          int qrow = m * 16 + (l >> 4) * 4 + r;
          outS[(long)qrow * N + g] = acc[m][n][r] * rn;
        }
      }
    }
  }
}

// ---------------- top-k helpers ----------------
__device__ __forceinline__ void insert10(float v, float p, float bs[10], float bi[10]) {
  bool last = (v > bs[9]) || (v == bs[9] && p < bi[9]);
  if (!last) return;
  #pragma unroll
  for (int j = 9; j >= 1; --j) {
    bool bj  = (v > bs[j])   || (v == bs[j]   && p < bi[j]);
    bool bjm = (v > bs[j-1]) || (v == bs[j-1] && p < bi[j-1]);
    float ns = bj ? (bjm ? bs[j-1] : v) : bs[j];
    float ni = bj ? (bjm ? bi[j-1] : p) : bi[j];
    bs[j] = ns; bi[j] = ni;
  }
  bool b0 = (v > bs[0]) || (v == bs[0] && p < bi[0]);
  if (b0) { bs[0] = v; bi[0] = p; }
}

// shared-LDS 256-thread top-10 merge; result in ms/mi[0]
__device__ __forceinline__ void blockmerge10(float bs[10], float bi[10],
                                             float (*ms)[10], float (*mi)[10],
                                             int t) {
  #pragma unroll
  for (int k = 0; k < 10; ++k) { ms[t][k] = bs[k]; mi[t][k] = bi[k]; }
  __syncthreads();
  for (int h = 128; h > 0; h >>= 1) {
    if (t < h) {
      float os[10], oi[10];
      int x = 0, y = 0;
      #pragma unroll
      for (int k = 0; k < 10; ++k) {
        float sx = ms[t][x], sy = ms[t + h][y];
        float ix = mi[t][x], iy = mi[t + h][y];
        bool ta = (sx > sy) || (sx == sy && ix < iy);
        os[k] = ta ? sx : sy; oi[k] = ta ? ix : iy;
        x += ta ? 1 : 0; y += ta ? 0 : 1;
      }
      #pragma unroll
      for (int k = 0; k < 10; ++k) { ms[t][k] = os[k]; mi[t][k] = oi[k]; }
    }
    __syncthreads();
  }
}

// ---------------- K4: per-(row, segment) top-10 on MFMA scores ----------------
__global__ __launch_bounds__(256) void k_topblk(const float* __restrict__ scores,
                                                float2* __restrict__ btop, int N) {
  const int row = blockIdx.y, seg = blockIdx.x, t = threadIdx.x;
  const int per = (N + NBK - 1) / NBK;
  const int s0 = seg * per;
  const int s1 = (s0 + per < N) ? (s0 + per) : N;
  const float* rp = scores + (long)row * N;
  float bs[10], bi[10];
  #pragma unroll
  for (int k = 0; k < 10; ++k) { bs[k] = -INFINITY; bi[k] = 2.0e9f; }
  for (int p = s0 + t; p < s1; p += 256) insert10(rp[p], (float)p, bs, bi);

  __shared__ float ms[256][10];
  __shared__ float mi[256][10];
  blockmerge10(bs, bi, ms, mi, t);
  if (t == 0) {
    #pragma unroll
    for (int k = 0; k < 10; ++k)
      btop[((long)row * NBK + seg) * 10 + k] = make_float2(ms[0][k], mi[0][k]);
  }
}

// ---------------- K5a: exact f32 rescore, parallel over 8 segments/row -------
// bf16 MFMA scores (~1e-4 err) only pick CANDIDATES; exact f32 rescore fixes
// the ranking. grid (NSEG, B): 256 blocks -> all CUs busy (r12's single-round
// 32-block version was ~80us latency-bound).
__global__ __launch_bounds__(256) void k_rescore(const float* __restrict__ docs,
                                                 const float* __restrict__ qn,
                                                 const float2* __restrict__ btop,
                                                 float2* __restrict__ btop2, int N) {
  const int seg = blockIdx.x, row = blockIdx.y, t = threadIdx.x;
  __shared__ float4 qrow[DF4];
  if (t < DF4) qrow[t] = ((const float4*)qn)[row * DF4 + t];
  __syncthreads();
  float bs[10], bi[10];
  #pragma unroll
  for (int k = 0; k < 10; ++k) { bs[k] = -INFINITY; bi[k] = 2.0e9f; }
  if (t < CPS) {
    float2 c = btop[(long)row * (NBK * 10) + seg * CPS + t];
    int doc = (int)c.y;
    const float4* dp = (const float4*)docs + (long)doc * DF4;
    float a0 = 0.f, a1 = 0.f, a2 = 0.f, a3 = 0.f;
    float s0 = 0.f, s1 = 0.f, s2 = 0.f, s3 = 0.f;
    for (int kk = 0; kk < DF4; ++kk) {
      float4 d4 = dp[kk]; float4 q4 = qrow[kk];
      a0 = fmaf(q4.x, d4.x, a0); a1 = fmaf(q4.y, d4.y, a1);
      a2 = fmaf(q4.z, d4.z, a2); a3 = fmaf(q4.w, d4.w, a3);
      s0 = fmaf(d4.x, d4.x, s0); s1 = fmaf(d4.y, d4.y, s1);
      s2 = fmaf(d4.z, d4.z, s2); s3 = fmaf(d4.w, d4.w, s3);
    }
    float nrm = sqrtf((s0 + s1) + (s2 + s3));
    insert10(((a0 + a1) + (a2 + a3)) / fmaxf(nrm, 1e-12f), c.y, bs, bi);
  }
  __shared__ float ms[256][10];
  __shared__ float mi[256][10];
  blockmerge10(bs, bi, ms, mi, t);
  if (t == 0) {
    #pragma unroll
    for (int k = 0; k < 10; ++k)
      btop2[((long)row * NSEG + seg) * 10 + k] = make_float2(ms[0][k], mi[0][k]);
  }
}

// ---------------- K5b: final 80 -> 10 merge per row --------------------------
__global__ __launch_bounds__(256) void k_topfinal(const float2* __restrict__ btop2,
                                                  float* __restrict__ outIdx) {
  const int row = blockIdx.x, t = threadIdx.x;
  const int M = NSEG * 10;   // 80
  float bs[10], bi[10];
  #pragma unroll
  for (int k = 0; k < 10; ++k) { bs[k] = -INFINITY; bi[k] = 2.0e9f; }
  if (t < M) {
    float2 c = btop2[(long)row * M + t];
    insert10(c.x, c.y, bs, bi);
  }
  __shared__ float ms[256][10];
  __shared__ float mi[256][10];
  blockmerge10(bs, bi, ms, mi, t);
  if (t == 0) {
    #pragma unroll
    for (int k = 0; k < 10; ++k) outIdx[row * TOPK + k] = mi[0][k];
  }
}

extern "C" void kernel_launch(void* const* d_in, const int* in_sizes, int n_in,
                              void* d_out, int out_size, void* d_ws, size_t ws_size,
                              hipStream_t stream) {
  const float* q    = (const float*)d_in[0];   // [32,128,768]
  const float* docs = (const float*)d_in[1];   // [N,768]
  const float* W    = (const float*)d_in[2];   // [768,768]
  const float* bias = (const float*)d_in[3];   // [768]
  const int B = in_sizes[0] / (SEQ * D);       // 32
  const int N = in_sizes[1] / D;               // 500000

  float* out    = (float*)d_out;
  float* outIdx = out;                          // [B*10] indices as float
  float* outS   = out + (long)B * TOPK;         // [B][N] scores

  float* qmean = (float*)d_ws;                               // B*D f32
  float* qnorm = qmean + (long)B * D;                        // B*D f32
  unsigned short* qbf = (unsigned short*)(qnorm + (long)B * D); // B*D bf16 swz
  float2* btop  = (float2*)((char*)qbf + (long)B * D * 2);   // B*NBK*10
  float2* btop2 = btop + (long)B * NBK * 10;                 // B*NSEG*10

  dim3 g1(3, B);
  k_mean<<<g1, 256, 0, stream>>>(q, qmean);
  k_proj<<<B, 256, 0, stream>>>(qmean, W, bias, qnorm, qbf);
  int ntiles = (N + TN - 1) / TN;
  k_scores<<<ntiles, 256, 0, stream>>>(docs, qbf, outS, N);
  dim3 g4(NBK, B);
  k_topblk<<<g4, 256, 0, stream>>>(outS, btop, N);
  dim3 g5(NSEG, B);
  k_rescore<<<g5, 256, 0, stream>>>(docs, qnorm, btop, btop2, N);
  k_topfinal<<<B, 256, 0, stream>>>(btop2, outIdx);
}